// Round 6
// baseline (140.246 us; speedup 1.0000x reference)
//
#include <hip/hip_runtime.h>

#define NQ 4
#define DEPTH 2
#define BLK 256
#define K 8           // elements per thread = 4 element-pairs packed in pk lanes
#define NPAIR (K / 2)

typedef float v2f __attribute__((ext_vector_type(2)));
typedef float v4f __attribute__((ext_vector_type(4)));

// ---- forced packed-fp32 math (all-VGPR operands; op_sel broadcasts u.lo/u.hi) ----
__device__ __forceinline__ void pk_fma_lo(v2f& acc, v2f u, v2f b) {
    asm("v_pk_fma_f32 %0, %1, %2, %0 op_sel:[0,0,0] op_sel_hi:[0,1,1]"
        : "+v"(acc) : "v"(u), "v"(b));
}
__device__ __forceinline__ void pk_fma_hi(v2f& acc, v2f u, v2f b) {
    asm("v_pk_fma_f32 %0, %1, %2, %0 op_sel:[1,0,0] op_sel_hi:[1,1,1]"
        : "+v"(acc) : "v"(u), "v"(b));
}
__device__ __forceinline__ v2f pk_mul(v2f a, v2f b) {
    v2f d;
    asm("v_pk_mul_f32 %0, %1, %2" : "=v"(d) : "v"(a), "v"(b));
    return d;
}
__device__ __forceinline__ void pk_fma(v2f& acc, v2f a, v2f b) {
    asm("v_pk_fma_f32 %0, %1, %2, %0" : "+v"(acc) : "v"(a), "v"(b));
}

__device__ __forceinline__ float2 cmul(float2 a, float2 b) {
    return make_float2(a.x * b.x - a.y * b.y, a.x * b.y + a.y * b.x);
}
__device__ __forceinline__ float2 cadd(float2 a, float2 b) {
    return make_float2(a.x + b.x, a.y + b.y);
}

// Simulate basis column `col` of the fixed post-encoding circuit unitary.
// __noinline__ keeps the builder's registers out of the main path's allocation.
__device__ __noinline__ void build_u_col(const float* __restrict__ qw, int col,
                                         float2 amp[16]) {
#pragma unroll
    for (int i = 0; i < 16; i++)
        amp[i] = make_float2((i == col) ? 1.f : 0.f, 0.f);

#pragma unroll
    for (int layer = 0; layer < DEPTH; layer++) {
#pragma unroll
        for (int w = 0; w < NQ; w++) {
            const float* g = qw + (layer * NQ + w) * 3;
            float phi = g[0], theta = g[1], omega = g[2];
            float ch, sh, sp, cp, sm, cm;
            __sincosf(0.5f * theta, &sh, &ch);
            __sincosf(-0.5f * (phi + omega), &sp, &cp);
            __sincosf(0.5f * (phi - omega), &sm, &cm);
            float2 U00 = make_float2(cp * ch, sp * ch);
            float2 U01 = make_float2(-cm * sh, -sm * sh);
            float2 U10 = make_float2(cm * sh, -sm * sh);
            float2 U11 = make_float2(cp * ch, -sp * ch);
            const int mask = 8 >> w;                      // wire w = bit (3-w)
#pragma unroll
            for (int i0 = 0; i0 < 16; i0++) {
                if (i0 & mask) continue;
                const int i1 = i0 | mask;
                float2 a0 = amp[i0], a1 = amp[i1];
                amp[i0] = cadd(cmul(U00, a0), cmul(U01, a1));
                amp[i1] = cadd(cmul(U10, a0), cmul(U11, a1));
            }
        }
        // CNOT ring: (0,1),(1,2),(2,3),(3,0)
#pragma unroll
        for (int c = 0; c < NQ; c++) {
            const int t = (c + 1) & 3;
            const int cmsk = 8 >> c, tmsk = 8 >> t;
#pragma unroll
            for (int i = 0; i < 16; i++) {
                if ((i & cmsk) && !(i & tmsk)) {
                    float2 tmp = amp[i];
                    amp[i] = amp[i | tmsk];
                    amp[i | tmsk] = tmp;
                }
            }
        }
    }
}

// Single fused kernel: threads 0..15 build U (16x16 complex, row-major) into
// LDS; then all threads run the batched matvec with K=8 elements each.
__global__ __launch_bounds__(BLK) void vqc_kernel(const float* __restrict__ x,
                                                  const float* __restrict__ qw,
                                                  float* __restrict__ out, int B) {
    __shared__ __align__(16) v2f Um[256];   // Um[row*16 + col] = {re, im}

    const int tid = threadIdx.x;
    if (tid < 16) {
        float2 amp[16];
        build_u_col(qw, tid, amp);
#pragma unroll
        for (int i = 0; i < 16; i++) {
            v2f u; u.x = amp[i].x; u.y = amp[i].y;
            Um[i * 16 + tid] = u;
        }
    }
    __syncthreads();

    const int base = blockIdx.x * (BLK * K) + tid;

    // ---- RY encoding: tensor factors, element-pair packed in pk lanes ----
    float4 xv[K];
    bool val[K];
#pragma unroll
    for (int k = 0; k < K; k++) {
        const int b = base + k * BLK;
        val[k] = (b < B);
        xv[k] = val[k] ? ((const float4*)x)[b] : make_float4(0.f, 0.f, 0.f, 0.f);
    }
    const float R = 0.07957747154594767f;   // 1/(4*pi): sin(x/2)=v_sin(x*R)
    v2f a01p[NPAIR][4], a23p[NPAIR][4];
#pragma unroll
    for (int p = 0; p < NPAIR; p++) {
        float a01[2][4], a23[2][4];
#pragma unroll
        for (int e = 0; e < 2; e++) {
            const float4 v = xv[2 * p + e];
            float s0 = __builtin_amdgcn_sinf(v.x * R), c0 = __builtin_amdgcn_cosf(v.x * R);
            float s1 = __builtin_amdgcn_sinf(v.y * R), c1 = __builtin_amdgcn_cosf(v.y * R);
            float s2 = __builtin_amdgcn_sinf(v.z * R), c2 = __builtin_amdgcn_cosf(v.z * R);
            float s3 = __builtin_amdgcn_sinf(v.w * R), c3 = __builtin_amdgcn_cosf(v.w * R);
            a01[e][0] = c0 * c1; a01[e][1] = c0 * s1; a01[e][2] = s0 * c1; a01[e][3] = s0 * s1;
            a23[e][0] = c2 * c3; a23[e][1] = c2 * s3; a23[e][2] = s2 * c3; a23[e][3] = s2 * s3;
        }
#pragma unroll
        for (int i = 0; i < 4; i++) {
            v2f t0; t0.x = a01[0][i]; t0.y = a01[1][i]; a01p[p][i] = t0;
            v2f t1; t1.x = a23[0][i]; t1.y = a23[1][i]; a23p[p][i] = t1;
        }
    }

    v2f ow[4][NPAIR];
#pragma unroll
    for (int w = 0; w < 4; w++)
#pragma unroll
        for (int p = 0; p < NPAIR; p++) ow[w][p] = (v2f)0.f;

    // ---- matvec: rows in pairs, cols in pairs; U from LDS as v4f ----
#pragma unroll
    for (int rp = 0; rp < 8; rp++) {
        v2f re0[NPAIR], im0[NPAIR], re1[NPAIR], im1[NPAIR];
#pragma unroll
        for (int p = 0; p < NPAIR; p++) {
            re0[p] = (v2f)0.f; im0[p] = (v2f)0.f;
            re1[p] = (v2f)0.f; im1[p] = (v2f)0.f;
        }
#pragma unroll
        for (int jp = 0; jp < 8; jp++) {
            const int ja = 2 * jp, jb = 2 * jp + 1;
            const v4f q0 = *(const v4f*)&Um[(2 * rp) * 16 + ja];       // row 2rp, cols ja,jb
            const v4f q1 = *(const v4f*)&Um[(2 * rp + 1) * 16 + ja];   // row 2rp+1
            const v2f u0a = __builtin_shufflevector(q0, q0, 0, 1);
            const v2f u0b = __builtin_shufflevector(q0, q0, 2, 3);
            const v2f u1a = __builtin_shufflevector(q1, q1, 0, 1);
            const v2f u1b = __builtin_shufflevector(q1, q1, 2, 3);
#pragma unroll
            for (int p = 0; p < NPAIR; p++) {
                const v2f psa = pk_mul(a01p[p][ja >> 2], a23p[p][ja & 3]);
                const v2f psb = pk_mul(a01p[p][jb >> 2], a23p[p][jb & 3]);
                pk_fma_lo(re0[p], u0a, psa); pk_fma_hi(im0[p], u0a, psa);
                pk_fma_lo(re0[p], u0b, psb); pk_fma_hi(im0[p], u0b, psb);
                pk_fma_lo(re1[p], u1a, psa); pk_fma_hi(im1[p], u1a, psa);
                pk_fma_lo(re1[p], u1b, psb); pk_fma_hi(im1[p], u1b, psb);
            }
        }
        // probs + signed accumulation. Row indices i0=2rp (bit0=0), i1=2rp+1.
        const int b3 = (rp >> 2) & 1, b2 = (rp >> 1) & 1, b1 = rp & 1;
#pragma unroll
        for (int p = 0; p < NPAIR; p++) {
            v2f p0 = pk_mul(re0[p], re0[p]); pk_fma(p0, im0[p], im0[p]);
            v2f p1 = pk_mul(re1[p], re1[p]); pk_fma(p1, im1[p], im1[p]);
            const v2f s = p0 + p1, d = p0 - p1;
            if (b3) ow[0][p] -= s; else ow[0][p] += s;   // wire0 ~ bit3
            if (b2) ow[1][p] -= s; else ow[1][p] += s;   // wire1 ~ bit2
            if (b1) ow[2][p] -= s; else ow[2][p] += s;   // wire2 ~ bit1
            ow[3][p] += d;                               // wire3 ~ bit0
        }
    }

    // ---- store: element k = 2p+e, lane component e ----
#pragma unroll
    for (int p = 0; p < NPAIR; p++)
#pragma unroll
        for (int e = 0; e < 2; e++) {
            const int k = 2 * p + e;
            const int b = base + k * BLK;
            if (val[k]) {
                float4 o;
                o.x = (e == 0) ? ow[0][p].x : ow[0][p].y;
                o.y = (e == 0) ? ow[1][p].x : ow[1][p].y;
                o.z = (e == 0) ? ow[2][p].x : ow[2][p].y;
                o.w = (e == 0) ? ow[3][p].x : ow[3][p].y;
                ((float4*)out)[b] = o;
            }
        }
}

extern "C" void kernel_launch(void* const* d_in, const int* in_sizes, int n_in,
                              void* d_out, int out_size, void* d_ws, size_t ws_size,
                              hipStream_t stream) {
    const float* x  = (const float*)d_in[0];
    const float* qw = (const float*)d_in[1];
    float* out = (float*)d_out;
    const int B = in_sizes[0] / NQ;
    const int blocks = (B + BLK * K - 1) / (BLK * K);
    vqc_kernel<<<blocks, BLK, 0, stream>>>(x, qw, out, B);
}

// Round 7
// 122.971 us; speedup vs baseline: 1.1405x; 1.1405x over previous
//
#include <hip/hip_runtime.h>

#define NQ 4
#define DEPTH 2
#define BLK 256
#define K 8           // elements per thread = 4 element-pairs packed in pk lanes
#define NPAIR (K / 2)

typedef float v2f __attribute__((ext_vector_type(2)));
typedef float v4f __attribute__((ext_vector_type(4)));

// ---- forced packed-fp32 math (all-VGPR operands; op_sel broadcasts u.lo/u.hi) ----
__device__ __forceinline__ void pk_fma_lo(v2f& acc, v2f u, v2f b) {
    asm("v_pk_fma_f32 %0, %1, %2, %0 op_sel:[0,0,0] op_sel_hi:[0,1,1]"
        : "+v"(acc) : "v"(u), "v"(b));
}
__device__ __forceinline__ void pk_fma_hi(v2f& acc, v2f u, v2f b) {
    asm("v_pk_fma_f32 %0, %1, %2, %0 op_sel:[1,0,0] op_sel_hi:[1,1,1]"
        : "+v"(acc) : "v"(u), "v"(b));
}
__device__ __forceinline__ v2f pk_mul(v2f a, v2f b) {
    v2f d;
    asm("v_pk_mul_f32 %0, %1, %2" : "=v"(d) : "v"(a), "v"(b));
    return d;
}
__device__ __forceinline__ void pk_fma(v2f& acc, v2f a, v2f b) {
    asm("v_pk_fma_f32 %0, %1, %2, %0" : "+v"(acc) : "v"(a), "v"(b));
}

__device__ __forceinline__ float2 cmul(float2 a, float2 b) {
    return make_float2(a.x * b.x - a.y * b.y, a.x * b.y + a.y * b.x);
}
__device__ __forceinline__ float2 cadd(float2 a, float2 b) {
    return make_float2(a.x + b.x, a.y + b.y);
}

// Simulate basis column `col` of the fixed post-encoding circuit unitary.
// INLINE (R6's __noinline__ forced amp[] to scratch + serial qw reloads).
__device__ __forceinline__ void build_u_col(const float* __restrict__ qw, int col,
                                            float2 amp[16]) {
#pragma unroll
    for (int i = 0; i < 16; i++)
        amp[i] = make_float2((i == col) ? 1.f : 0.f, 0.f);

#pragma unroll
    for (int layer = 0; layer < DEPTH; layer++) {
#pragma unroll
        for (int w = 0; w < NQ; w++) {
            const float* g = qw + (layer * NQ + w) * 3;
            float phi = g[0], theta = g[1], omega = g[2];
            float ch, sh, sp, cp, sm, cm;
            __sincosf(0.5f * theta, &sh, &ch);
            __sincosf(-0.5f * (phi + omega), &sp, &cp);
            __sincosf(0.5f * (phi - omega), &sm, &cm);
            float2 U00 = make_float2(cp * ch, sp * ch);
            float2 U01 = make_float2(-cm * sh, -sm * sh);
            float2 U10 = make_float2(cm * sh, -sm * sh);
            float2 U11 = make_float2(cp * ch, -sp * ch);
            const int mask = 8 >> w;                      // wire w = bit (3-w)
#pragma unroll
            for (int i0 = 0; i0 < 16; i0++) {
                if (i0 & mask) continue;
                const int i1 = i0 | mask;
                float2 a0 = amp[i0], a1 = amp[i1];
                amp[i0] = cadd(cmul(U00, a0), cmul(U01, a1));
                amp[i1] = cadd(cmul(U10, a0), cmul(U11, a1));
            }
        }
        // CNOT ring: (0,1),(1,2),(2,3),(3,0)
#pragma unroll
        for (int c = 0; c < NQ; c++) {
            const int t = (c + 1) & 3;
            const int cmsk = 8 >> c, tmsk = 8 >> t;
#pragma unroll
            for (int i = 0; i < 16; i++) {
                if ((i & cmsk) && !(i & tmsk)) {
                    float2 tmp = amp[i];
                    amp[i] = amp[i | tmsk];
                    amp[i | tmsk] = tmp;
                }
            }
        }
    }
}

// Kernel A: one tiny block computes U (16x16 complex) into global scratch.
__global__ void build_u_kernel(const float* __restrict__ qw, v2f* __restrict__ Ug) {
    const int tid = threadIdx.x;
    if (tid < 16) {
        float2 amp[16];
        build_u_col(qw, tid, amp);
#pragma unroll
        for (int i = 0; i < 16; i++) {
            v2f u; u.x = amp[i].x; u.y = amp[i].y;
            Ug[i * 16 + tid] = u;   // row-major [i][j]
        }
    }
}

// Main matvec body: U in LDS (row-major v2f[256]), K=8 elements per thread.
__device__ __forceinline__ void vqc_matvec_body(const float* __restrict__ x,
                                                const v2f* Um,
                                                float* __restrict__ out, int B) {
    const int tid = threadIdx.x;
    const int base = blockIdx.x * (BLK * K) + tid;

    // ---- RY encoding: tensor factors, element-pair packed in pk lanes ----
    float4 xv[K];
    bool val[K];
#pragma unroll
    for (int k = 0; k < K; k++) {
        const int b = base + k * BLK;
        val[k] = (b < B);
        xv[k] = val[k] ? ((const float4*)x)[b] : make_float4(0.f, 0.f, 0.f, 0.f);
    }
    const float R = 0.07957747154594767f;   // 1/(4*pi): sin(x/2)=v_sin(x*R)
    v2f a01p[NPAIR][4], a23p[NPAIR][4];
#pragma unroll
    for (int p = 0; p < NPAIR; p++) {
        float a01[2][4], a23[2][4];
#pragma unroll
        for (int e = 0; e < 2; e++) {
            const float4 v = xv[2 * p + e];
            float s0 = __builtin_amdgcn_sinf(v.x * R), c0 = __builtin_amdgcn_cosf(v.x * R);
            float s1 = __builtin_amdgcn_sinf(v.y * R), c1 = __builtin_amdgcn_cosf(v.y * R);
            float s2 = __builtin_amdgcn_sinf(v.z * R), c2 = __builtin_amdgcn_cosf(v.z * R);
            float s3 = __builtin_amdgcn_sinf(v.w * R), c3 = __builtin_amdgcn_cosf(v.w * R);
            a01[e][0] = c0 * c1; a01[e][1] = c0 * s1; a01[e][2] = s0 * c1; a01[e][3] = s0 * s1;
            a23[e][0] = c2 * c3; a23[e][1] = c2 * s3; a23[e][2] = s2 * c3; a23[e][3] = s2 * s3;
        }
#pragma unroll
        for (int i = 0; i < 4; i++) {
            v2f t0; t0.x = a01[0][i]; t0.y = a01[1][i]; a01p[p][i] = t0;
            v2f t1; t1.x = a23[0][i]; t1.y = a23[1][i]; a23p[p][i] = t1;
        }
    }

    v2f ow[4][NPAIR];
#pragma unroll
    for (int w = 0; w < 4; w++)
#pragma unroll
        for (int p = 0; p < NPAIR; p++) ow[w][p] = (v2f)0.f;

    // ---- matvec: rows in pairs, cols in pairs; U from LDS as v4f ----
#pragma unroll
    for (int rp = 0; rp < 8; rp++) {
        v2f re0[NPAIR], im0[NPAIR], re1[NPAIR], im1[NPAIR];
#pragma unroll
        for (int p = 0; p < NPAIR; p++) {
            re0[p] = (v2f)0.f; im0[p] = (v2f)0.f;
            re1[p] = (v2f)0.f; im1[p] = (v2f)0.f;
        }
#pragma unroll
        for (int jp = 0; jp < 8; jp++) {
            const int ja = 2 * jp, jb = 2 * jp + 1;
            const v4f q0 = *(const v4f*)&Um[(2 * rp) * 16 + ja];       // row 2rp
            const v4f q1 = *(const v4f*)&Um[(2 * rp + 1) * 16 + ja];   // row 2rp+1
            const v2f u0a = __builtin_shufflevector(q0, q0, 0, 1);
            const v2f u0b = __builtin_shufflevector(q0, q0, 2, 3);
            const v2f u1a = __builtin_shufflevector(q1, q1, 0, 1);
            const v2f u1b = __builtin_shufflevector(q1, q1, 2, 3);
#pragma unroll
            for (int p = 0; p < NPAIR; p++) {
                const v2f psa = pk_mul(a01p[p][ja >> 2], a23p[p][ja & 3]);
                const v2f psb = pk_mul(a01p[p][jb >> 2], a23p[p][jb & 3]);
                pk_fma_lo(re0[p], u0a, psa); pk_fma_hi(im0[p], u0a, psa);
                pk_fma_lo(re0[p], u0b, psb); pk_fma_hi(im0[p], u0b, psb);
                pk_fma_lo(re1[p], u1a, psa); pk_fma_hi(im1[p], u1a, psa);
                pk_fma_lo(re1[p], u1b, psb); pk_fma_hi(im1[p], u1b, psb);
            }
        }
        // probs + signed accumulation. Rows i0=2rp (bit0=0), i1=2rp+1.
        const int b3 = (rp >> 2) & 1, b2 = (rp >> 1) & 1, b1 = rp & 1;
#pragma unroll
        for (int p = 0; p < NPAIR; p++) {
            v2f p0 = pk_mul(re0[p], re0[p]); pk_fma(p0, im0[p], im0[p]);
            v2f p1 = pk_mul(re1[p], re1[p]); pk_fma(p1, im1[p], im1[p]);
            const v2f s = p0 + p1, d = p0 - p1;
            if (b3) ow[0][p] -= s; else ow[0][p] += s;   // wire0 ~ bit3
            if (b2) ow[1][p] -= s; else ow[1][p] += s;   // wire1 ~ bit2
            if (b1) ow[2][p] -= s; else ow[2][p] += s;   // wire2 ~ bit1
            ow[3][p] += d;                               // wire3 ~ bit0
        }
    }

    // ---- store: element k = 2p+e, lane component e ----
#pragma unroll
    for (int p = 0; p < NPAIR; p++)
#pragma unroll
        for (int e = 0; e < 2; e++) {
            const int k = 2 * p + e;
            const int b = base + k * BLK;
            if (val[k]) {
                float4 o;
                o.x = (e == 0) ? ow[0][p].x : ow[0][p].y;
                o.y = (e == 0) ? ow[1][p].x : ow[1][p].y;
                o.z = (e == 0) ? ow[2][p].x : ow[2][p].y;
                o.w = (e == 0) ? ow[3][p].x : ow[3][p].y;
                ((float4*)out)[b] = o;
            }
        }
}

// Kernel B: stage precomputed U (2 KB) into LDS with a plain copy, run matvec.
__global__ __launch_bounds__(BLK) void vqc_main(const float* __restrict__ x,
                                                const v4f* __restrict__ Ug,
                                                float* __restrict__ out, int B) {
    __shared__ __align__(16) v2f Um[256];
    if (threadIdx.x < 128) ((v4f*)Um)[threadIdx.x] = Ug[threadIdx.x];
    __syncthreads();
    vqc_matvec_body(x, Um, out, B);
}

// Fallback if ws is too small (normally unused): inline in-block builder.
__global__ void vqc_fused(const float* __restrict__ x, const float* __restrict__ qw,
                          float* __restrict__ out, int B) {
    __shared__ __align__(16) v2f Um[256];
    if (threadIdx.x < 16) {
        float2 amp[16];
        build_u_col(qw, threadIdx.x, amp);
#pragma unroll
        for (int i = 0; i < 16; i++) {
            v2f u; u.x = amp[i].x; u.y = amp[i].y;
            Um[i * 16 + threadIdx.x] = u;
        }
    }
    __syncthreads();
    vqc_matvec_body(x, Um, out, B);
}

extern "C" void kernel_launch(void* const* d_in, const int* in_sizes, int n_in,
                              void* d_out, int out_size, void* d_ws, size_t ws_size,
                              hipStream_t stream) {
    const float* x  = (const float*)d_in[0];
    const float* qw = (const float*)d_in[1];
    float* out = (float*)d_out;
    const int B = in_sizes[0] / NQ;
    const int blocks = (B + BLK * K - 1) / (BLK * K);

    if (ws_size >= 256 * sizeof(v2f)) {
        v2f* Ug = (v2f*)d_ws;
        build_u_kernel<<<1, 64, 0, stream>>>(qw, Ug);
        vqc_main<<<blocks, BLK, 0, stream>>>(x, (const v4f*)Ug, out, B);
    } else {
        vqc_fused<<<blocks, BLK, 0, stream>>>(x, qw, out, B);
    }
}

// Round 8
// 114.410 us; speedup vs baseline: 1.2258x; 1.0748x over previous
//
#include <hip/hip_runtime.h>

#define NQ 4
#define DEPTH 2
#define BLK 256
#define K 8           // elements per thread = 4 element-pairs packed in pk lanes
#define NPAIR (K / 2)

typedef float v2f __attribute__((ext_vector_type(2)));
typedef float v4f __attribute__((ext_vector_type(4)));

// ---- forced packed-fp32 math (all-VGPR operands; op_sel broadcasts u.lo/u.hi) ----
__device__ __forceinline__ void pk_fma_lo(v2f& acc, v2f u, v2f b) {
    asm("v_pk_fma_f32 %0, %1, %2, %0 op_sel:[0,0,0] op_sel_hi:[0,1,1]"
        : "+v"(acc) : "v"(u), "v"(b));
}
__device__ __forceinline__ void pk_fma_hi(v2f& acc, v2f u, v2f b) {
    asm("v_pk_fma_f32 %0, %1, %2, %0 op_sel:[1,0,0] op_sel_hi:[1,1,1]"
        : "+v"(acc) : "v"(u), "v"(b));
}
__device__ __forceinline__ v2f pk_mul(v2f a, v2f b) {
    v2f d;
    asm("v_pk_mul_f32 %0, %1, %2" : "=v"(d) : "v"(a), "v"(b));
    return d;
}
__device__ __forceinline__ void pk_fma(v2f& acc, v2f a, v2f b) {
    asm("v_pk_fma_f32 %0, %1, %2, %0" : "+v"(acc) : "v"(a), "v"(b));
}

__device__ __forceinline__ float2 cmul(float2 a, float2 b) {
    return make_float2(a.x * b.x - a.y * b.y, a.x * b.y + a.y * b.x);
}
__device__ __forceinline__ float2 cadd(float2 a, float2 b) {
    return make_float2(a.x + b.x, a.y + b.y);
}

// Simulate basis column `col` of the fixed post-encoding circuit unitary.
// INLINE (R6 showed __noinline__ forces amp[] to scratch + serial qw reloads).
__device__ __forceinline__ void build_u_col(const float* __restrict__ qw, int col,
                                            float2 amp[16]) {
#pragma unroll
    for (int i = 0; i < 16; i++)
        amp[i] = make_float2((i == col) ? 1.f : 0.f, 0.f);

#pragma unroll
    for (int layer = 0; layer < DEPTH; layer++) {
#pragma unroll
        for (int w = 0; w < NQ; w++) {
            const float* g = qw + (layer * NQ + w) * 3;
            float phi = g[0], theta = g[1], omega = g[2];
            float ch, sh, sp, cp, sm, cm;
            __sincosf(0.5f * theta, &sh, &ch);
            __sincosf(-0.5f * (phi + omega), &sp, &cp);
            __sincosf(0.5f * (phi - omega), &sm, &cm);
            float2 U00 = make_float2(cp * ch, sp * ch);
            float2 U01 = make_float2(-cm * sh, -sm * sh);
            float2 U10 = make_float2(cm * sh, -sm * sh);
            float2 U11 = make_float2(cp * ch, -sp * ch);
            const int mask = 8 >> w;                      // wire w = bit (3-w)
#pragma unroll
            for (int i0 = 0; i0 < 16; i0++) {
                if (i0 & mask) continue;
                const int i1 = i0 | mask;
                float2 a0 = amp[i0], a1 = amp[i1];
                amp[i0] = cadd(cmul(U00, a0), cmul(U01, a1));
                amp[i1] = cadd(cmul(U10, a0), cmul(U11, a1));
            }
        }
        // CNOT ring: (0,1),(1,2),(2,3),(3,0)
#pragma unroll
        for (int c = 0; c < NQ; c++) {
            const int t = (c + 1) & 3;
            const int cmsk = 8 >> c, tmsk = 8 >> t;
#pragma unroll
            for (int i = 0; i < 16; i++) {
                if ((i & cmsk) && !(i & tmsk)) {
                    float2 tmp = amp[i];
                    amp[i] = amp[i | tmsk];
                    amp[i | tmsk] = tmp;
                }
            }
        }
    }
}

// Kernel A: one tiny block computes U (16x16 complex) into global scratch.
__global__ void build_u_kernel(const float* __restrict__ qw, v2f* __restrict__ Ug) {
    const int tid = threadIdx.x;
    if (tid < 16) {
        float2 amp[16];
        build_u_col(qw, tid, amp);
#pragma unroll
        for (int i = 0; i < 16; i++) {
            v2f u; u.x = amp[i].x; u.y = amp[i].y;
            Ug[i * 16 + tid] = u;   // row-major [i][j]
        }
    }
}

// Main matvec body: U in LDS (row-major v2f[256]), K=8 elements per thread.
// rp loop intentionally NOT unrolled: keeps the hot body ~3 KB (I-cache
// resident, 8 trips) instead of 25 KB straight-line (R7: 30% VALUBusy).
__device__ __forceinline__ void vqc_matvec_body(const float* __restrict__ x,
                                                const v2f* Um,
                                                float* __restrict__ out, int B) {
    const int tid = threadIdx.x;
    const int base = blockIdx.x * (BLK * K) + tid;

    // ---- RY encoding: tensor factors, element-pair packed in pk lanes ----
    float4 xv[K];
    bool val[K];
#pragma unroll
    for (int k = 0; k < K; k++) {
        const int b = base + k * BLK;
        val[k] = (b < B);
        xv[k] = val[k] ? ((const float4*)x)[b] : make_float4(0.f, 0.f, 0.f, 0.f);
    }
    const float R = 0.07957747154594767f;   // 1/(4*pi): sin(x/2)=v_sin(x*R)
    v2f a01p[NPAIR][4], a23p[NPAIR][4];
#pragma unroll
    for (int p = 0; p < NPAIR; p++) {
        float a01[2][4], a23[2][4];
#pragma unroll
        for (int e = 0; e < 2; e++) {
            const float4 v = xv[2 * p + e];
            float s0 = __builtin_amdgcn_sinf(v.x * R), c0 = __builtin_amdgcn_cosf(v.x * R);
            float s1 = __builtin_amdgcn_sinf(v.y * R), c1 = __builtin_amdgcn_cosf(v.y * R);
            float s2 = __builtin_amdgcn_sinf(v.z * R), c2 = __builtin_amdgcn_cosf(v.z * R);
            float s3 = __builtin_amdgcn_sinf(v.w * R), c3 = __builtin_amdgcn_cosf(v.w * R);
            a01[e][0] = c0 * c1; a01[e][1] = c0 * s1; a01[e][2] = s0 * c1; a01[e][3] = s0 * s1;
            a23[e][0] = c2 * c3; a23[e][1] = c2 * s3; a23[e][2] = s2 * c3; a23[e][3] = s2 * s3;
        }
#pragma unroll
        for (int i = 0; i < 4; i++) {
            v2f t0; t0.x = a01[0][i]; t0.y = a01[1][i]; a01p[p][i] = t0;
            v2f t1; t1.x = a23[0][i]; t1.y = a23[1][i]; a23p[p][i] = t1;
        }
    }

    v2f ow[4][NPAIR];
#pragma unroll
    for (int w = 0; w < 4; w++)
#pragma unroll
        for (int p = 0; p < NPAIR; p++) ow[w][p] = (v2f)0.f;

    // ---- matvec: row-pair loop (LOOPED), col-pairs unrolled inside ----
#pragma unroll 1
    for (int rp = 0; rp < 8; rp++) {
        // wave-uniform signs for this row pair (rows 2rp, 2rp+1)
        const float f3 = (rp & 4) ? -1.f : 1.f;   // bit3 of row -> wire0
        const float f2 = (rp & 2) ? -1.f : 1.f;   // bit2 -> wire1
        const float f1 = (rp & 1) ? -1.f : 1.f;   // bit1 -> wire2
        v2f sg3; sg3.x = f3; sg3.y = f3;
        v2f sg2; sg2.x = f2; sg2.y = f2;
        v2f sg1; sg1.x = f1; sg1.y = f1;

        v2f re0[NPAIR], im0[NPAIR], re1[NPAIR], im1[NPAIR];
#pragma unroll
        for (int p = 0; p < NPAIR; p++) {
            re0[p] = (v2f)0.f; im0[p] = (v2f)0.f;
            re1[p] = (v2f)0.f; im1[p] = (v2f)0.f;
        }
#pragma unroll
        for (int jp = 0; jp < 8; jp++) {
            const int ja = 2 * jp, jb = 2 * jp + 1;
            const v4f q0 = *(const v4f*)&Um[(2 * rp) * 16 + ja];       // row 2rp
            const v4f q1 = *(const v4f*)&Um[(2 * rp + 1) * 16 + ja];   // row 2rp+1
            const v2f u0a = __builtin_shufflevector(q0, q0, 0, 1);
            const v2f u0b = __builtin_shufflevector(q0, q0, 2, 3);
            const v2f u1a = __builtin_shufflevector(q1, q1, 0, 1);
            const v2f u1b = __builtin_shufflevector(q1, q1, 2, 3);
#pragma unroll
            for (int p = 0; p < NPAIR; p++) {
                const v2f psa = pk_mul(a01p[p][ja >> 2], a23p[p][ja & 3]);
                const v2f psb = pk_mul(a01p[p][jb >> 2], a23p[p][jb & 3]);
                pk_fma_lo(re0[p], u0a, psa); pk_fma_hi(im0[p], u0a, psa);
                pk_fma_lo(re0[p], u0b, psb); pk_fma_hi(im0[p], u0b, psb);
                pk_fma_lo(re1[p], u1a, psa); pk_fma_hi(im1[p], u1a, psa);
                pk_fma_lo(re1[p], u1b, psb); pk_fma_hi(im1[p], u1b, psb);
            }
        }
        // probs + signed accumulation (rows i0=2rp bit0=0, i1=2rp+1 bit0=1)
#pragma unroll
        for (int p = 0; p < NPAIR; p++) {
            v2f p0 = pk_mul(re0[p], re0[p]); pk_fma(p0, im0[p], im0[p]);
            v2f p1 = pk_mul(re1[p], re1[p]); pk_fma(p1, im1[p], im1[p]);
            const v2f s = p0 + p1, d = p0 - p1;
            pk_fma(ow[0][p], sg3, s);
            pk_fma(ow[1][p], sg2, s);
            pk_fma(ow[2][p], sg1, s);
            ow[3][p] += d;               // wire3 ~ bit0
        }
    }

    // ---- store: element k = 2p+e, lane component e ----
#pragma unroll
    for (int p = 0; p < NPAIR; p++)
#pragma unroll
        for (int e = 0; e < 2; e++) {
            const int k = 2 * p + e;
            const int b = base + k * BLK;
            if (val[k]) {
                float4 o;
                o.x = (e == 0) ? ow[0][p].x : ow[0][p].y;
                o.y = (e == 0) ? ow[1][p].x : ow[1][p].y;
                o.z = (e == 0) ? ow[2][p].x : ow[2][p].y;
                o.w = (e == 0) ? ow[3][p].x : ow[3][p].y;
                ((float4*)out)[b] = o;
            }
        }
}

// Kernel B: stage precomputed U (2 KB) into LDS with a plain copy, run matvec.
__global__ __launch_bounds__(BLK) void vqc_main(const float* __restrict__ x,
                                                const v4f* __restrict__ Ug,
                                                float* __restrict__ out, int B) {
    __shared__ __align__(16) v2f Um[256];
    if (threadIdx.x < 128) ((v4f*)Um)[threadIdx.x] = Ug[threadIdx.x];
    __syncthreads();
    vqc_matvec_body(x, Um, out, B);
}

// Fallback if ws is too small (normally unused): inline in-block builder.
__global__ void vqc_fused(const float* __restrict__ x, const float* __restrict__ qw,
                          float* __restrict__ out, int B) {
    __shared__ __align__(16) v2f Um[256];
    if (threadIdx.x < 16) {
        float2 amp[16];
        build_u_col(qw, threadIdx.x, amp);
#pragma unroll
        for (int i = 0; i < 16; i++) {
            v2f u; u.x = amp[i].x; u.y = amp[i].y;
            Um[i * 16 + threadIdx.x] = u;
        }
    }
    __syncthreads();
    vqc_matvec_body(x, Um, out, B);
}

extern "C" void kernel_launch(void* const* d_in, const int* in_sizes, int n_in,
                              void* d_out, int out_size, void* d_ws, size_t ws_size,
                              hipStream_t stream) {
    const float* x  = (const float*)d_in[0];
    const float* qw = (const float*)d_in[1];
    float* out = (float*)d_out;
    const int B = in_sizes[0] / NQ;
    const int blocks = (B + BLK * K - 1) / (BLK * K);

    if (ws_size >= 256 * sizeof(v2f)) {
        v2f* Ug = (v2f*)d_ws;
        build_u_kernel<<<1, 64, 0, stream>>>(qw, Ug);
        vqc_main<<<blocks, BLK, 0, stream>>>(x, (const v4f*)Ug, out, B);
    } else {
        vqc_fused<<<blocks, BLK, 0, stream>>>(x, qw, out, B);
    }
}

// Round 9
// 105.179 us; speedup vs baseline: 1.3334x; 1.0878x over previous
//
#include <hip/hip_runtime.h>

#define NQ 4
#define DEPTH 2
#define BLK 256
#define K 4           // elements per thread

typedef _Float16 v2h __attribute__((ext_vector_type(2)));

// dot2: f32 += f16[0]*f16[0] + f16[1]*f16[1]  (full-rate DL instruction)
__device__ __forceinline__ float fdot2u(unsigned u, unsigned p, float acc) {
#if __has_builtin(__builtin_amdgcn_fdot2)
    return __builtin_amdgcn_fdot2(__builtin_bit_cast(v2h, u),
                                  __builtin_bit_cast(v2h, p), acc, false);
#else
    float d;
    asm("v_dot2_f32_f16 %0, %1, %2, %3" : "=v"(d) : "v"(u), "v"(p), "v"(acc));
    return d;
#endif
}
__device__ __forceinline__ unsigned pack2h(float a, float b) {
    return __builtin_bit_cast(unsigned, __builtin_amdgcn_cvt_pkrtz(a, b));
}

__device__ __forceinline__ float2 cmul(float2 a, float2 b) {
    return make_float2(a.x * b.x - a.y * b.y, a.x * b.y + a.y * b.x);
}
__device__ __forceinline__ float2 cadd(float2 a, float2 b) {
    return make_float2(a.x + b.x, a.y + b.y);
}

// Simulate basis column `col` of the fixed post-encoding circuit unitary.
__device__ __forceinline__ void build_u_col(const float* __restrict__ qw, int col,
                                            float2 amp[16]) {
#pragma unroll
    for (int i = 0; i < 16; i++)
        amp[i] = make_float2((i == col) ? 1.f : 0.f, 0.f);

#pragma unroll
    for (int layer = 0; layer < DEPTH; layer++) {
#pragma unroll
        for (int w = 0; w < NQ; w++) {
            const float* g = qw + (layer * NQ + w) * 3;
            float phi = g[0], theta = g[1], omega = g[2];
            float ch, sh, sp, cp, sm, cm;
            __sincosf(0.5f * theta, &sh, &ch);
            __sincosf(-0.5f * (phi + omega), &sp, &cp);
            __sincosf(0.5f * (phi - omega), &sm, &cm);
            float2 U00 = make_float2(cp * ch, sp * ch);
            float2 U01 = make_float2(-cm * sh, -sm * sh);
            float2 U10 = make_float2(cm * sh, -sm * sh);
            float2 U11 = make_float2(cp * ch, -sp * ch);
            const int mask = 8 >> w;                      // wire w = bit (3-w)
#pragma unroll
            for (int i0 = 0; i0 < 16; i0++) {
                if (i0 & mask) continue;
                const int i1 = i0 | mask;
                float2 a0 = amp[i0], a1 = amp[i1];
                amp[i0] = cadd(cmul(U00, a0), cmul(U01, a1));
                amp[i1] = cadd(cmul(U10, a0), cmul(U11, a1));
            }
        }
        // CNOT ring: (0,1),(1,2),(2,3),(3,0)
#pragma unroll
        for (int c = 0; c < NQ; c++) {
            const int t = (c + 1) & 3;
            const int cmsk = 8 >> c, tmsk = 8 >> t;
#pragma unroll
            for (int i = 0; i < 16; i++) {
                if ((i & cmsk) && !(i & tmsk)) {
                    float2 tmp = amp[i];
                    amp[i] = amp[i | tmsk];
                    amp[i | tmsk] = tmp;
                }
            }
        }
    }
}

// Kernel A: one tiny block computes U and stores f16 planes into scratch:
// ws[0..255] = re plane (row-major 16x16 f16), ws[256..511] = im plane. 1 KB.
__global__ void build_u_kernel(const float* __restrict__ qw, _Float16* __restrict__ Uw) {
    const int tid = threadIdx.x;
    if (tid < 16) {
        float2 amp[16];
        build_u_col(qw, tid, amp);
        _Float16* wre = Uw;
        _Float16* wim = Uw + 256;
#pragma unroll
        for (int i = 0; i < 16; i++) {
            wre[i * 16 + tid] = (_Float16)amp[i].x;
            wim[i * 16 + tid] = (_Float16)amp[i].y;
        }
    }
}

// Main body: Upl = LDS with 256 dwords: [0..127] re plane (row r = dwords
// 8r..8r+7, dword q = f16 pair (j=2q, 2q+1)), [128..255] im plane.
__device__ __forceinline__ void vqc_body(const float* __restrict__ x,
                                         const unsigned* Upl,
                                         float* __restrict__ out, int B) {
    const int tid = threadIdx.x;
    const int base = blockIdx.x * (BLK * K) + tid;

    // ---- RY encoding -> psi in f16 pairs over j ----
    bool val[K];
    unsigned psh[K][8];     // psh[el][q] = {psi[2q], psi[2q+1]} as 2xf16
#pragma unroll
    for (int k = 0; k < K; k++) {
        const int b = base + k * BLK;
        val[k] = (b < B);
        const float4 v = val[k] ? ((const float4*)x)[b] : make_float4(0.f, 0.f, 0.f, 0.f);
        const float R = 0.07957747154594767f;   // 1/(4*pi): sin(x/2)=v_sin(x*R)
        float s0 = __builtin_amdgcn_sinf(v.x * R), c0 = __builtin_amdgcn_cosf(v.x * R);
        float s1 = __builtin_amdgcn_sinf(v.y * R), c1 = __builtin_amdgcn_cosf(v.y * R);
        float s2 = __builtin_amdgcn_sinf(v.z * R), c2 = __builtin_amdgcn_cosf(v.z * R);
        float s3 = __builtin_amdgcn_sinf(v.w * R), c3 = __builtin_amdgcn_cosf(v.w * R);
        const float a01[4] = {c0 * c1, c0 * s1, s0 * c1, s0 * s1};
        const float a23[4] = {c2 * c3, c2 * s3, s2 * c3, s2 * s3};
#pragma unroll
        for (int q = 0; q < 8; q++) {
            const int j0 = 2 * q, j1 = 2 * q + 1;
            psh[k][q] = pack2h(a01[j0 >> 2] * a23[j0 & 3], a01[j1 >> 2] * a23[j1 & 3]);
        }
    }

    float ow0[K], ow1[K], ow2[K], ow3[K];
#pragma unroll
    for (int k = 0; k < K; k++) { ow0[k] = 0.f; ow1[k] = 0.f; ow2[k] = 0.f; ow3[k] = 0.f; }

    // ---- matvec: row-pair loop (kept as a real loop for I-cache) ----
#pragma unroll 1
    for (int rp = 0; rp < 8; rp++) {
        const int r0 = 2 * rp;
        const uint4 re0a = *(const uint4*)&Upl[r0 * 8];
        const uint4 re0b = *(const uint4*)&Upl[r0 * 8 + 4];
        const uint4 re1a = *(const uint4*)&Upl[(r0 + 1) * 8];
        const uint4 re1b = *(const uint4*)&Upl[(r0 + 1) * 8 + 4];
        const uint4 im0a = *(const uint4*)&Upl[128 + r0 * 8];
        const uint4 im0b = *(const uint4*)&Upl[128 + r0 * 8 + 4];
        const uint4 im1a = *(const uint4*)&Upl[128 + (r0 + 1) * 8];
        const uint4 im1b = *(const uint4*)&Upl[128 + (r0 + 1) * 8 + 4];
        const unsigned ur0[8] = {re0a.x, re0a.y, re0a.z, re0a.w, re0b.x, re0b.y, re0b.z, re0b.w};
        const unsigned ur1[8] = {re1a.x, re1a.y, re1a.z, re1a.w, re1b.x, re1b.y, re1b.z, re1b.w};
        const unsigned ui0[8] = {im0a.x, im0a.y, im0a.z, im0a.w, im0b.x, im0b.y, im0b.z, im0b.w};
        const unsigned ui1[8] = {im1a.x, im1a.y, im1a.z, im1a.w, im1b.x, im1b.y, im1b.z, im1b.w};

        const float f3 = (rp & 4) ? -1.f : 1.f;   // bit3 of row -> wire0
        const float f2 = (rp & 2) ? -1.f : 1.f;   // bit2 -> wire1
        const float f1 = (rp & 1) ? -1.f : 1.f;   // bit1 -> wire2

#pragma unroll
        for (int k = 0; k < K; k++) {
            float fre0 = 0.f, fim0 = 0.f, fre1 = 0.f, fim1 = 0.f;
#pragma unroll
            for (int q = 0; q < 8; q++) {
                const unsigned p = psh[k][q];
                fre0 = fdot2u(ur0[q], p, fre0);
                fim0 = fdot2u(ui0[q], p, fim0);
                fre1 = fdot2u(ur1[q], p, fre1);
                fim1 = fdot2u(ui1[q], p, fim1);
            }
            const float p0 = fmaf(fim0, fim0, fre0 * fre0);
            const float p1 = fmaf(fim1, fim1, fre1 * fre1);
            const float s = p0 + p1, d = p0 - p1;
            ow0[k] = fmaf(f3, s, ow0[k]);
            ow1[k] = fmaf(f2, s, ow1[k]);
            ow2[k] = fmaf(f1, s, ow2[k]);
            ow3[k] += d;                          // bit0 -> wire3
        }
    }

#pragma unroll
    for (int k = 0; k < K; k++) {
        const int b = base + k * BLK;
        if (val[k])
            ((float4*)out)[b] = make_float4(ow0[k], ow1[k], ow2[k], ow3[k]);
    }
}

// Kernel B: stage the 1 KB f16 U-planes into LDS, run the dot2 matvec.
__global__ __launch_bounds__(BLK) void vqc_main(const float* __restrict__ x,
                                                const uint4* __restrict__ Uw,
                                                float* __restrict__ out, int B) {
    __shared__ __align__(16) unsigned Upl[256];
    if (threadIdx.x < 64) ((uint4*)Upl)[threadIdx.x] = Uw[threadIdx.x];
    __syncthreads();
    vqc_body(x, Upl, out, B);
}

// Fallback if ws too small (normally unused): build U in-block into LDS planes.
__global__ void vqc_fused(const float* __restrict__ x, const float* __restrict__ qw,
                          float* __restrict__ out, int B) {
    __shared__ __align__(16) unsigned Upl[256];
    if (threadIdx.x < 16) {
        float2 amp[16];
        build_u_col(qw, threadIdx.x, amp);
        _Float16* wre = (_Float16*)Upl;
        _Float16* wim = wre + 256;
#pragma unroll
        for (int i = 0; i < 16; i++) {
            wre[i * 16 + threadIdx.x] = (_Float16)amp[i].x;
            wim[i * 16 + threadIdx.x] = (_Float16)amp[i].y;
        }
    }
    __syncthreads();
    vqc_body(x, Upl, out, B);
}

extern "C" void kernel_launch(void* const* d_in, const int* in_sizes, int n_in,
                              void* d_out, int out_size, void* d_ws, size_t ws_size,
                              hipStream_t stream) {
    const float* x  = (const float*)d_in[0];
    const float* qw = (const float*)d_in[1];
    float* out = (float*)d_out;
    const int B = in_sizes[0] / NQ;
    const int blocks = (B + BLK * K - 1) / (BLK * K);

    if (ws_size >= 1024) {
        build_u_kernel<<<1, 64, 0, stream>>>(qw, (_Float16*)d_ws);
        vqc_main<<<blocks, BLK, 0, stream>>>(x, (const uint4*)d_ws, out, B);
    } else {
        vqc_fused<<<blocks, BLK, 0, stream>>>(x, qw, out, B);
    }
}